// Round 3
// baseline (194.517 us; speedup 1.0000x reference)
//
#include <hip/hip_runtime.h>

typedef __attribute__((ext_vector_type(8))) short bh8;   // 8 bf16
typedef __attribute__((ext_vector_type(4))) float fx4;   // mfma acc

__device__ __forceinline__ unsigned short f2bf(float f) {
  unsigned u = __float_as_uint(f);
  u += 0x7FFFu + ((u >> 16) & 1u);     // RNE
  return (unsigned short)(u >> 16);
}

__device__ __forceinline__ bh8 pack8(float4 u, float4 v) {
  bh8 r;
  r[0] = (short)f2bf(u.x); r[1] = (short)f2bf(u.y);
  r[2] = (short)f2bf(u.z); r[3] = (short)f2bf(u.w);
  r[4] = (short)f2bf(v.x); r[5] = (short)f2bf(v.y);
  r[6] = (short)f2bf(v.z); r[7] = (short)f2bf(v.w);
  return r;
}

// ---------------- K0: BT[b][o][3m+j] = sum_f x[b][m][f]*Wcat[o][j*32+f] (bf16) -----
// grid 256 (8 b x 32 chunks of 32 m), block 256.
__global__ void __launch_bounds__(256) k0_bt(const float* __restrict__ x,
    const float* __restrict__ W1, const float* __restrict__ W2,
    unsigned short* __restrict__ bt) {
  __shared__ float xl[32][32];     // 4 KB
  __shared__ float wl[96][64];     // 24 KB, wl[k][o]
  int t = threadIdx.x;
  int bid = blockIdx.x;
  int b = bid >> 5, c = bid & 31;

  for (int i = t; i < 3072; i += 256) {       // coalesced W loads
    int r = i / 96, k = i - r * 96;
    wl[k][r]      = W1[i];
    wl[k][r + 32] = W2[i];
  }
  const float4* xs = (const float4*)(x + (size_t)(b * 1024 + c * 32) * 32);
  ((float4*)xl)[t] = xs[t];
  __syncthreads();

  int o = t & 63;
  int q = t >> 6;
  int m0 = q * 8;
  float acc[8][3];
#pragma unroll
  for (int m = 0; m < 8; ++m) acc[m][0] = acc[m][1] = acc[m][2] = 0.f;
#pragma unroll
  for (int f4 = 0; f4 < 8; ++f4) {
    float wv[3][4];
#pragma unroll
    for (int u = 0; u < 4; ++u) {
      int f = f4 * 4 + u;
      wv[0][u] = wl[f][o];
      wv[1][u] = wl[32 + f][o];
      wv[2][u] = wl[64 + f][o];
    }
#pragma unroll
    for (int m = 0; m < 8; ++m) {
      float4 xv = *(const float4*)&xl[m0 + m][f4 * 4];
#pragma unroll
      for (int j = 0; j < 3; ++j) {
        acc[m][j] = fmaf(xv.x, wv[j][0], acc[m][j]);
        acc[m][j] = fmaf(xv.y, wv[j][1], acc[m][j]);
        acc[m][j] = fmaf(xv.z, wv[j][2], acc[m][j]);
        acc[m][j] = fmaf(xv.w, wv[j][3], acc[m][j]);
      }
    }
  }
  unsigned pk[12];
#pragma unroll
  for (int i = 0; i < 12; ++i) {
    unsigned short lo = f2bf(acc[(2 * i) / 3][(2 * i) % 3]);
    unsigned short hi = f2bf(acc[(2 * i + 1) / 3][(2 * i + 1) % 3]);
    pk[i] = (unsigned)lo | ((unsigned)hi << 16);
  }
  unsigned short* orow = bt + (size_t)(b * 64 + o) * 3072;
  uint4* op = (uint4*)(orow + 3 * (c * 32 + m0));     // 48B-aligned
  op[0] = make_uint4(pk[0], pk[1], pk[2], pk[3]);
  op[1] = make_uint4(pk[4], pk[5], pk[6], pk[7]);
  op[2] = make_uint4(pk[8], pk[9], pk[10], pk[11]);
}

// ---------------- K1: LDS-free barrier-free GEMM, K-split x8 -----------------------
// grid 1024 (128 mtiles x 8 ksplits), block 256 (4 indep waves, 16 rows each).
// A fragments: direct coalesced f32 global loads (16 rows x 128B per inst), cvt in reg.
// B fragments: per-lane 16B loads from BT (L2-resident, 3MB).
__global__ void __launch_bounds__(256) k1_gemm(const float* __restrict__ A,
    const unsigned short* __restrict__ BT, float* __restrict__ parts) {
  int t = threadIdx.x;
  int w = t >> 6, l = t & 63;
  int lr = l & 15, lg = l >> 4;
  int bid = blockIdx.x;
  int ks = bid & 7, mt = bid >> 3;
  int arow = mt * 64 + w * 16 + lr;
  int b = mt >> 4;
  int kbase = ks * 384 + lg * 8;
  const float* ap = A + (size_t)arow * 3072 + kbase;
  const unsigned short* bp = BT + (size_t)b * 196608 + (size_t)lr * 3072 + kbase;

  fx4 acc0 = {0.f,0.f,0.f,0.f}, acc1 = {0.f,0.f,0.f,0.f};
  fx4 acc2 = {0.f,0.f,0.f,0.f}, acc3 = {0.f,0.f,0.f,0.f};

#define LOADA_(s, ra, rb) { ra = *(const float4*)(ap + (s) * 32); \
                            rb = *(const float4*)(ap + (s) * 32 + 4); }
#define LOADB_(s, c0, c1, c2, c3) { \
    c0 = *(const bh8*)(bp + (s) * 32); \
    c1 = *(const bh8*)(bp + 49152 + (s) * 32); \
    c2 = *(const bh8*)(bp + 98304 + (s) * 32); \
    c3 = *(const bh8*)(bp + 147456 + (s) * 32); }
#define STEP_(ra, rb, c0, c1, c2, c3) { bh8 av = pack8(ra, rb); \
    acc0 = __builtin_amdgcn_mfma_f32_16x16x32_bf16(av, c0, acc0, 0, 0, 0); \
    acc1 = __builtin_amdgcn_mfma_f32_16x16x32_bf16(av, c1, acc1, 0, 0, 0); \
    acc2 = __builtin_amdgcn_mfma_f32_16x16x32_bf16(av, c2, acc2, 0, 0, 0); \
    acc3 = __builtin_amdgcn_mfma_f32_16x16x32_bf16(av, c3, acc3, 0, 0, 0); }

  float4 aA0, aA1, aB0, aB1;
  bh8 bA0, bA1, bA2, bA3, bB0, bB1, bB2, bB3;
  LOADA_(0, aA0, aA1); LOADB_(0, bA0, bA1, bA2, bA3);
  LOADA_(1, aB0, aB1); LOADB_(1, bB0, bB1, bB2, bB3);
#pragma unroll
  for (int s = 0; s < 12; s += 2) {
    STEP_(aA0, aA1, bA0, bA1, bA2, bA3);
    if (s + 2 < 12) { LOADA_(s + 2, aA0, aA1); LOADB_(s + 2, bA0, bA1, bA2, bA3); }
    STEP_(aB0, aB1, bB0, bB1, bB2, bB3);
    if (s + 3 < 12) { LOADA_(s + 3, aB0, aB1); LOADB_(s + 3, bB0, bB1, bB2, bB3); }
  }
#undef LOADA_
#undef LOADB_
#undef STEP_

  // D frag: col = lane&15 (= o within o-tile), row = (lane>>4)*4 + reg
  float* pout = parts + ((size_t)ks * 8192 + (size_t)mt * 64 + w * 16) * 64;
#pragma unroll
  for (int r = 0; r < 4; ++r) {
    int ro = (lg * 4 + r) * 64 + lr;
    pout[ro]      = acc0[r];
    pout[ro + 16] = acc1[r];
    pout[ro + 32] = acc2[r];
    pout[ro + 48] = acc3[r];
  }
}

// ---------------- K2: sum 8 partials + bias + relu -> z, BN per-block sums ---------
__global__ void __launch_bounds__(256) k2_red(const float* __restrict__ parts,
    const float* __restrict__ b1, const float* __restrict__ b2,
    float* __restrict__ z, float2* __restrict__ part2) {
  __shared__ float4 redA[4][16], redB[4][16];
  int t = threadIdx.x, bid = blockIdx.x;
  int w = t >> 6, l = t & 63;
  int o0 = (t & 15) * 4;
  float4 bias = (o0 < 32) ? ((const float4*)b1)[o0 >> 2]
                          : ((const float4*)b2)[(o0 - 32) >> 2];
  bool rl = (o0 < 32);
  float4 s1 = {0.f, 0.f, 0.f, 0.f}, s2 = {0.f, 0.f, 0.f, 0.f};
  const float4* p0 = (const float4*)parts;
#pragma unroll
  for (int kk = 0; kk < 4; ++kk) {
    int i4 = bid * 1024 + kk * 256 + t;
    float4 v = p0[i4];
#pragma unroll
    for (int j = 1; j < 8; ++j) {
      float4 vj = p0[j * 131072 + i4];
      v.x += vj.x; v.y += vj.y; v.z += vj.z; v.w += vj.w;
    }
    v.x += bias.x; v.y += bias.y; v.z += bias.z; v.w += bias.w;
    if (rl) {
      v.x = fmaxf(v.x, 0.f); v.y = fmaxf(v.y, 0.f);
      v.z = fmaxf(v.z, 0.f); v.w = fmaxf(v.w, 0.f);
    }
    ((float4*)z)[i4] = v;
    s1.x += v.x; s1.y += v.y; s1.z += v.z; s1.w += v.w;
    s2.x += v.x * v.x; s2.y += v.y * v.y; s2.z += v.z * v.z; s2.w += v.w * v.w;
  }
#define RED_(c) { s1.c += __shfl_xor(s1.c, 16); s1.c += __shfl_xor(s1.c, 32); \
                  s2.c += __shfl_xor(s2.c, 16); s2.c += __shfl_xor(s2.c, 32); }
  RED_(x) RED_(y) RED_(z) RED_(w)
#undef RED_
  if (l < 16) { redA[w][l] = s1; redB[w][l] = s2; }
  __syncthreads();
  if (t < 16) {
    float4 S = redA[0][t], Q = redB[0][t];
#pragma unroll
    for (int wv = 1; wv < 4; ++wv) {
      float4 a = redA[wv][t], q = redB[wv][t];
      S.x += a.x; S.y += a.y; S.z += a.z; S.w += a.w;
      Q.x += q.x; Q.y += q.y; Q.z += q.z; Q.w += q.w;
    }
    int ob = bid * 64 + t * 4;
    part2[ob + 0] = make_float2(S.x, Q.x);
    part2[ob + 1] = make_float2(S.y, Q.y);
    part2[ob + 2] = make_float2(S.z, Q.z);
    part2[ob + 3] = make_float2(S.w, Q.w);
  }
}

// ---------------- K3: reduce 128 block-partials -> scale/shift ---------------------
__global__ void k3_stats(const float2* __restrict__ part2, const float* __restrict__ gamma,
                         const float* __restrict__ beta, float2* __restrict__ stats) {
  __shared__ float red[2][4][64];
  int t = threadIdx.x;           // 256
  int o = t & 63, c = t >> 6;    // c 0..3
  float S = 0.f, Q = 0.f;
#pragma unroll 4
  for (int i = 0; i < 32; ++i) {
    float2 p = part2[(c * 32 + i) * 64 + o];
    S += p.x; Q += p.y;
  }
  red[0][c][o] = S; red[1][c][o] = Q;
  __syncthreads();
  if (t < 64) {
    float Ss = 0.f, Qs = 0.f;
#pragma unroll
    for (int cc = 0; cc < 4; ++cc) { Ss += red[0][cc][t]; Qs += red[1][cc][t]; }
    float mean = Ss * (1.0f / 8192.0f);
    float var = fmaxf(Qs * (1.0f / 8192.0f) - mean * mean, 0.f);
    float rstd = rsqrtf(var + 1e-5f);
    float scale = gamma[t] * rstd;
    stats[t] = make_float2(scale, beta[t] - mean * scale);
  }
}

// ---------------- K4: normalize in place on d_out ----------------------------------
__global__ void k4_norm(float* __restrict__ z, const float2* __restrict__ stats) {
  int i4 = blockIdx.x * 256 + threadIdx.x;   // 131072 float4's
  float4 v = ((const float4*)z)[i4];
  int o0 = (i4 & 15) * 4;
  float2 s0 = stats[o0 + 0], s1 = stats[o0 + 1], s2 = stats[o0 + 2], s3 = stats[o0 + 3];
  v.x = v.x * s0.x + s0.y;
  v.y = v.y * s1.x + s1.y;
  v.z = v.z * s2.x + s2.y;
  v.w = v.w * s3.x + s3.y;
  ((float4*)z)[i4] = v;
}

extern "C" void kernel_launch(void* const* d_in, const int* in_sizes, int n_in,
                              void* d_out, int out_size, void* d_ws, size_t ws_size,
                              hipStream_t stream) {
  const float* WW = (const float*)d_in[0];
  const float* x  = (const float*)d_in[1];
  const float* W1 = (const float*)d_in[2];
  const float* b1 = (const float*)d_in[3];
  const float* W2 = (const float*)d_in[4];
  const float* b2 = (const float*)d_in[5];
  const float* gamma = (const float*)d_in[6];
  const float* beta  = (const float*)d_in[7];

  unsigned short* bt = (unsigned short*)d_ws;                       //  3,145,728 B
  float*  parts = (float*)((char*)d_ws + 3145728);                  // 16,777,216 B
  float2* part2 = (float2*)((char*)d_ws + 3145728 + 16777216);      //     65,536 B
  float2* stats = (float2*)((char*)d_ws + 3145728 + 16777216 + 65536); //    512 B
  float* z = (float*)d_out;

  hipLaunchKernelGGL(k0_bt,    dim3(256),  dim3(256), 0, stream, x, W1, W2, bt);
  hipLaunchKernelGGL(k1_gemm,  dim3(1024), dim3(256), 0, stream, WW, bt, parts);
  hipLaunchKernelGGL(k2_red,   dim3(128),  dim3(256), 0, stream, parts, b1, b2, z, part2);
  hipLaunchKernelGGL(k3_stats, dim3(1),    dim3(256), 0, stream, part2, gamma, beta, stats);
  hipLaunchKernelGGL(k4_norm,  dim3(512),  dim3(256), 0, stream, z, stats);
}

// Round 4
// 184.717 us; speedup vs baseline: 1.0531x; 1.0531x over previous
//
#include <hip/hip_runtime.h>

typedef __attribute__((ext_vector_type(8))) short bh8;   // 8 bf16
typedef __attribute__((ext_vector_type(4))) float fx4;   // mfma acc

__device__ __forceinline__ unsigned short f2bf(float f) {
  unsigned u = __float_as_uint(f);
  u += 0x7FFFu + ((u >> 16) & 1u);     // RNE
  return (unsigned short)(u >> 16);
}

__device__ __forceinline__ bh8 pack8(float4 u, float4 v) {
  bh8 r;
  r[0] = (short)f2bf(u.x); r[1] = (short)f2bf(u.y);
  r[2] = (short)f2bf(u.z); r[3] = (short)f2bf(u.w);
  r[4] = (short)f2bf(v.x); r[5] = (short)f2bf(v.y);
  r[6] = (short)f2bf(v.z); r[7] = (short)f2bf(v.w);
  return r;
}

__device__ __forceinline__ void async_g2l16(const void* g, void* l) {
  __builtin_amdgcn_global_load_lds(
      (const __attribute__((address_space(1))) unsigned int*)g,
      (__attribute__((address_space(3))) unsigned int*)l, 16, 0, 0);
}

// ---------------- K0: build BT as the pre-swizzled LDS image -----------------------
// BT_ws[(b*8+ks)*49152 + o*768 + (kbyte ^ ((o&7)<<4))] = bf16 B^T[b][o][ks*384 + k]
// where kbyte = 2*k_within_ksplit.  grid 256 (8 b x 32 chunks of 32 m), block 256.
__global__ void __launch_bounds__(256) k0_bt(const float* __restrict__ x,
    const float* __restrict__ W1, const float* __restrict__ W2,
    unsigned char* __restrict__ bt) {
  __shared__ float xl[32][32];     // 4 KB
  __shared__ float wl[96][64];     // 24 KB, wl[k][o]
  int t = threadIdx.x;
  int bid = blockIdx.x;
  int b = bid >> 5, c = bid & 31;

  for (int i = t; i < 3072; i += 256) {       // coalesced W loads
    int r = i / 96, k = i - r * 96;
    wl[k][r]      = W1[i];
    wl[k][r + 32] = W2[i];
  }
  const float4* xs = (const float4*)(x + (size_t)(b * 1024 + c * 32) * 32);
  ((float4*)xl)[t] = xs[t];
  __syncthreads();

  int o = t & 63;
  int q = t >> 6;
  int m0 = q * 8;
  float acc[8][3];
#pragma unroll
  for (int m = 0; m < 8; ++m) acc[m][0] = acc[m][1] = acc[m][2] = 0.f;
#pragma unroll
  for (int f4 = 0; f4 < 8; ++f4) {
    float wv[3][4];
#pragma unroll
    for (int u = 0; u < 4; ++u) {
      int f = f4 * 4 + u;
      wv[0][u] = wl[f][o];
      wv[1][u] = wl[32 + f][o];
      wv[2][u] = wl[64 + f][o];
    }
#pragma unroll
    for (int m = 0; m < 8; ++m) {
      float4 xv = *(const float4*)&xl[m0 + m][f4 * 4];
#pragma unroll
      for (int j = 0; j < 3; ++j) {
        acc[m][j] = fmaf(xv.x, wv[j][0], acc[m][j]);
        acc[m][j] = fmaf(xv.y, wv[j][1], acc[m][j]);
        acc[m][j] = fmaf(xv.z, wv[j][2], acc[m][j]);
        acc[m][j] = fmaf(xv.w, wv[j][3], acc[m][j]);
      }
    }
  }
  unsigned pk[12];
#pragma unroll
  for (int i = 0; i < 12; ++i) {
    unsigned short lo = f2bf(acc[(2 * i) / 3][(2 * i) % 3]);
    unsigned short hi = f2bf(acc[(2 * i + 1) / 3][(2 * i + 1) % 3]);
    pk[i] = (unsigned)lo | ((unsigned)hi << 16);
  }
  int ks = c >> 2;
  int kb = (c & 3) * 192 + q * 48;            // byte base within 768B row
  int swz = (o & 7) << 4;
  unsigned char* ob = bt + (size_t)(b * 8 + ks) * 49152 + (size_t)o * 768;
  *(uint4*)(ob + ((kb     ) ^ swz)) = make_uint4(pk[0], pk[1], pk[2],  pk[3]);
  *(uint4*)(ob + ((kb + 16) ^ swz)) = make_uint4(pk[4], pk[5], pk[6],  pk[7]);
  *(uint4*)(ob + ((kb + 32) ^ swz)) = make_uint4(pk[8], pk[9], pk[10], pk[11]);
}

// ---------------- K1: streamed GEMM, async LDS ring + counted vmcnt ----------------
// grid 1024 (128 mtiles x 8 ksplits), block 256 (4 waves). BM=64, BN=64, BK=32.
// LDS: A ring 4x8KB @0 (f32, XOR-swizzled rows), B 48KB @32768 (bf16, pre-swizzled).
__global__ void __launch_bounds__(256, 2) k1_gemm(const float* __restrict__ A,
    const unsigned char* __restrict__ BTS, float* __restrict__ parts) {
  __shared__ __align__(16) unsigned char smem[81920];
  int t = threadIdx.x;
  int w = t >> 6, l = t & 63;
  int lr = l & 15, lg = l >> 4;
  int bid = blockIdx.x;
  int ks = bid & 7, mt = bid >> 3;
  int b = mt >> 4;
  int r0 = mt * 64;

  // ---- stage all of B (12 wave-instructions, fully linear) ----
  const unsigned char* bsrc = BTS + (size_t)(b * 8 + ks) * 49152 + w * 1024 + l * 16;
#pragma unroll
  for (int i = 0; i < 12; ++i)
    async_g2l16(bsrc + i * 4096, smem + 32768 + i * 4096 + w * 1024);

  // ---- A stage sources (pre-swizzled per-lane global address, linear LDS dest) ----
  int arow = w * 8 + (l >> 3);                       // r=0 round rows 0..31
  int insw = ((l & 7) ^ (l >> 3)) << 4;              // swizzled byte-in-128B-chunk
  const unsigned char* ab = (const unsigned char*)(A + (size_t)r0 * 3072 + ks * 384);
  const unsigned char* asrc0 = ab + (size_t)arow * 12288 + insw;
  const unsigned char* asrc1 = ab + (size_t)(arow + 32) * 12288 + insw;

#define STAGE_A(S) { \
    unsigned char* sl = smem + ((S) & 3) * 8192 + w * 1024; \
    async_g2l16(asrc0 + (S) * 128, sl); \
    async_g2l16(asrc1 + (S) * 128, sl + 4096); }

  fx4 acc0 = {0.f,0.f,0.f,0.f}, acc1 = {0.f,0.f,0.f,0.f};
  fx4 acc2 = {0.f,0.f,0.f,0.f}, acc3 = {0.f,0.f,0.f,0.f};

  int rb  = (w * 16 + lr) * 128;
  int asw = (lr & 7) << 4;
  const unsigned char* bl = smem + 32768 + lr * 768;

#define READ_MFMA(S) { \
    const unsigned char* sl = smem + ((S) & 3) * 8192; \
    float4 a0 = *(const float4*)(sl + rb + ((lg * 32     ) ^ asw)); \
    float4 a1 = *(const float4*)(sl + rb + ((lg * 32 + 16) ^ asw)); \
    bh8 av = pack8(a0, a1); \
    int kb = (S) * 64 + lg * 16; \
    bh8 b0 = *(const bh8*)(bl +     0 + (kb ^ asw)); \
    bh8 b1 = *(const bh8*)(bl + 12288 + (kb ^ asw)); \
    bh8 b2 = *(const bh8*)(bl + 24576 + (kb ^ asw)); \
    bh8 b3 = *(const bh8*)(bl + 36864 + (kb ^ asw)); \
    acc0 = __builtin_amdgcn_mfma_f32_16x16x32_bf16(av, b0, acc0, 0, 0, 0); \
    acc1 = __builtin_amdgcn_mfma_f32_16x16x32_bf16(av, b1, acc1, 0, 0, 0); \
    acc2 = __builtin_amdgcn_mfma_f32_16x16x32_bf16(av, b2, acc2, 0, 0, 0); \
    acc3 = __builtin_amdgcn_mfma_f32_16x16x32_bf16(av, b3, acc3, 0, 0, 0); }

#define KSTEP_S(S, NW) { \
    STAGE_A(S + 2); \
    asm volatile("s_waitcnt vmcnt(" #NW ")" ::: "memory"); \
    __builtin_amdgcn_s_barrier(); \
    __builtin_amdgcn_sched_barrier(0); \
    READ_MFMA(S); }

#define KSTEP_N(S, NW) { \
    asm volatile("s_waitcnt vmcnt(" #NW ")" ::: "memory"); \
    __builtin_amdgcn_s_barrier(); \
    __builtin_amdgcn_sched_barrier(0); \
    READ_MFMA(S); }

  STAGE_A(0);
  STAGE_A(1);

  KSTEP_S(0, 4)  KSTEP_S(1, 4)  KSTEP_S(2, 4)  KSTEP_S(3, 4)
  KSTEP_S(4, 4)  KSTEP_S(5, 4)  KSTEP_S(6, 4)  KSTEP_S(7, 4)
  KSTEP_S(8, 4)  KSTEP_S(9, 4)  KSTEP_N(10, 2) KSTEP_N(11, 0)

#undef STAGE_A
#undef READ_MFMA
#undef KSTEP_S
#undef KSTEP_N

  // D frag: col = lane&15 (o within tile), row = (lane>>4)*4 + reg
  float* pout = parts + ((size_t)ks * 8192 + (size_t)mt * 64 + w * 16) * 64;
#pragma unroll
  for (int r = 0; r < 4; ++r) {
    int ro = (lg * 4 + r) * 64 + lr;
    pout[ro]      = acc0[r];
    pout[ro + 16] = acc1[r];
    pout[ro + 32] = acc2[r];
    pout[ro + 48] = acc3[r];
  }
}

// ---------------- K2: sum 8 partials + bias + relu -> z, BN per-block sums ---------
__global__ void __launch_bounds__(256) k2_red(const float* __restrict__ parts,
    const float* __restrict__ b1, const float* __restrict__ b2,
    float* __restrict__ z, float2* __restrict__ part2) {
  __shared__ float4 redA[4][16], redB[4][16];
  int t = threadIdx.x, bid = blockIdx.x;
  int w = t >> 6, l = t & 63;
  int o0 = (t & 15) * 4;
  float4 bias = (o0 < 32) ? ((const float4*)b1)[o0 >> 2]
                          : ((const float4*)b2)[(o0 - 32) >> 2];
  bool rl = (o0 < 32);
  float4 s1 = {0.f, 0.f, 0.f, 0.f}, s2 = {0.f, 0.f, 0.f, 0.f};
  const float4* p0 = (const float4*)parts;
#pragma unroll
  for (int kk = 0; kk < 4; ++kk) {
    int i4 = bid * 1024 + kk * 256 + t;
    float4 v = p0[i4];
#pragma unroll
    for (int j = 1; j < 8; ++j) {
      float4 vj = p0[j * 131072 + i4];
      v.x += vj.x; v.y += vj.y; v.z += vj.z; v.w += vj.w;
    }
    v.x += bias.x; v.y += bias.y; v.z += bias.z; v.w += bias.w;
    if (rl) {
      v.x = fmaxf(v.x, 0.f); v.y = fmaxf(v.y, 0.f);
      v.z = fmaxf(v.z, 0.f); v.w = fmaxf(v.w, 0.f);
    }
    ((float4*)z)[i4] = v;
    s1.x += v.x; s1.y += v.y; s1.z += v.z; s1.w += v.w;
    s2.x += v.x * v.x; s2.y += v.y * v.y; s2.z += v.z * v.z; s2.w += v.w * v.w;
  }
#define RED_(c) { s1.c += __shfl_xor(s1.c, 16); s1.c += __shfl_xor(s1.c, 32); \
                  s2.c += __shfl_xor(s2.c, 16); s2.c += __shfl_xor(s2.c, 32); }
  RED_(x) RED_(y) RED_(z) RED_(w)
#undef RED_
  if (l < 16) { redA[w][l] = s1; redB[w][l] = s2; }
  __syncthreads();
  if (t < 16) {
    float4 S = redA[0][t], Q = redB[0][t];
#pragma unroll
    for (int wv = 1; wv < 4; ++wv) {
      float4 a = redA[wv][t], q = redB[wv][t];
      S.x += a.x; S.y += a.y; S.z += a.z; S.w += a.w;
      Q.x += q.x; Q.y += q.y; Q.z += q.z; Q.w += q.w;
    }
    int ob = bid * 64 + t * 4;
    part2[ob + 0] = make_float2(S.x, Q.x);
    part2[ob + 1] = make_float2(S.y, Q.y);
    part2[ob + 2] = make_float2(S.z, Q.z);
    part2[ob + 3] = make_float2(S.w, Q.w);
  }
}

// ---------------- K4: per-block redundant stats + normalize in place ---------------
__global__ void __launch_bounds__(256) k4_norm(const float2* __restrict__ part2,
    const float* __restrict__ gamma, const float* __restrict__ beta,
    float* __restrict__ z) {
  __shared__ float red[2][4][64];
  __shared__ float2 sstat[64];
  int t = threadIdx.x, bid = blockIdx.x;
  int o = t & 63, c = t >> 6;
  float S = 0.f, Q = 0.f;
#pragma unroll 4
  for (int i = 0; i < 32; ++i) {
    float2 p = part2[(c * 32 + i) * 64 + o];
    S += p.x; Q += p.y;
  }
  red[0][c][o] = S; red[1][c][o] = Q;
  __syncthreads();
  if (t < 64) {
    float Ss = 0.f, Qs = 0.f;
#pragma unroll
    for (int cc = 0; cc < 4; ++cc) { Ss += red[0][cc][t]; Qs += red[1][cc][t]; }
    float mean = Ss * (1.0f / 8192.0f);
    float var = fmaxf(Qs * (1.0f / 8192.0f) - mean * mean, 0.f);
    float rstd = rsqrtf(var + 1e-5f);
    float scale = gamma[t] * rstd;
    sstat[t] = make_float2(scale, beta[t] - mean * scale);
  }
  __syncthreads();
  int o0 = (t & 15) * 4;
  float2 s0 = sstat[o0], s1 = sstat[o0 + 1], s2 = sstat[o0 + 2], s3 = sstat[o0 + 3];
#pragma unroll
  for (int k = 0; k < 4; ++k) {
    int i4 = bid * 1024 + k * 256 + t;   // 128 blocks x 1024 float4
    float4 v = ((const float4*)z)[i4];
    v.x = v.x * s0.x + s0.y;
    v.y = v.y * s1.x + s1.y;
    v.z = v.z * s2.x + s2.y;
    v.w = v.w * s3.x + s3.y;
    ((float4*)z)[i4] = v;
  }
}

extern "C" void kernel_launch(void* const* d_in, const int* in_sizes, int n_in,
                              void* d_out, int out_size, void* d_ws, size_t ws_size,
                              hipStream_t stream) {
  const float* WW = (const float*)d_in[0];
  const float* x  = (const float*)d_in[1];
  const float* W1 = (const float*)d_in[2];
  const float* b1 = (const float*)d_in[3];
  const float* W2 = (const float*)d_in[4];
  const float* b2 = (const float*)d_in[5];
  const float* gamma = (const float*)d_in[6];
  const float* beta  = (const float*)d_in[7];

  unsigned char* bt = (unsigned char*)d_ws;                         //  3,145,728 B
  float*  parts = (float*)((char*)d_ws + 3145728);                  // 16,777,216 B
  float2* part2 = (float2*)((char*)d_ws + 3145728 + 16777216);      //     65,536 B
  float* z = (float*)d_out;

  hipLaunchKernelGGL(k0_bt,   dim3(256),  dim3(256), 0, stream, x, W1, W2, bt);
  hipLaunchKernelGGL(k1_gemm, dim3(1024), dim3(256), 0, stream, WW, bt, parts);
  hipLaunchKernelGGL(k2_red,  dim3(128),  dim3(256), 0, stream, parts, b1, b2, z, part2);
  hipLaunchKernelGGL(k4_norm, dim3(128),  dim3(256), 0, stream, part2, gamma, beta, z);
}